// Round 6
// baseline (279.420 us; speedup 1.0000x reference)
//
#include <hip/hip_runtime.h>

#define FEATS 64
#define HSZ   4096
#define ISZ   12480          // (FEATS+1)*FEATS*3
#define I4    (ISZ/4)        // 3120 float4
#define H4    (HSZ/4)        // 1024 float4

// workspace layout (float offsets)
#define X_OFF   0            // 12480
#define GI_OFF  12480        // 12288 (includes b_ih)
#define GH_OFF  24768        // 12288 (includes b_hh)
#define SYNC_OFF 37056       // int[2]: flag (GAT done), counter (blocks done)

#define NBLK 512
#define RPB  24              // rows per block per phase (both GI and GH)
#define RPW  6               // rows per wave

typedef float f4 __attribute__((ext_vector_type(4)));

__device__ __forceinline__ float wave_reduce(float v) {
    #pragma unroll
    for (int off = 32; off > 0; off >>= 1) v += __shfl_down(v, off);
    return v;
}

__device__ __forceinline__ float fma4(f4 w, f4 v, float a) {
    return fmaf(w.x, v.x, fmaf(w.y, v.y, fmaf(w.z, v.z, fmaf(w.w, v.w, a))));
}

__device__ __forceinline__ f4 ntload(const f4* p) {
    return __builtin_nontemporal_load(p);   // use-once weights: bypass L2 insert
}

// One dispatch does everything:
//   blocks 0,1: GAT (feat/time) -> x, release flag. Then their matvec shares.
//   all blocks: phase1 = 24 rows of W_hh@h0 (GAT-independent, hides GAT latency),
//               then wait flag==2, phase2 = 24 rows of W_ih@x.
//   last block (device counter): GRU combine -> out.
// Co-residency proof: launch_bounds(256,2) => VGPR<=256, LDS ~17KB => >=2 blk/CU
// => capacity >= 512 = grid, so all blocks resident; spin cannot deadlock.
__global__ __launch_bounds__(256, 2)
void mega(const float* __restrict__ data,
          const float* __restrict__ fW, const float* __restrict__ fal,
          const float* __restrict__ fb,
          const float* __restrict__ tW, const float* __restrict__ tal,
          const float* __restrict__ tb,
          const float* __restrict__ W_ih, const float* __restrict__ W_hh,
          const float* __restrict__ h0,
          const float* __restrict__ b_ih, const float* __restrict__ b_hh,
          float* __restrict__ ws, float* __restrict__ out) {
    __shared__ float hb[64][65];
    __shared__ float out0[64];
    __shared__ int   sLast;
    int b = blockIdx.x, tid = threadIdx.x;
    int wave = tid >> 6, lane = tid & 63;
    int* sync = (int*)(ws + SYNC_OFF);

    // ---------------- GAT producers (blocks 0,1) --------------------------------
    if (b < 2) {
        const float* Wg = b ? tW  : fW;
        const float* al = b ? tal : fal;
        const float* bb = b ? tb  : fb;
        // h = (b ? data^T : data) @ Wg ; wave owns 16 rows, lane = output col j
        int vbase = wave * 16, j = lane;
        float acc[16];
        #pragma unroll
        for (int v = 0; v < 16; ++v) acc[v] = 0.f;
        for (int k = 0; k < 64; ++k) {
            float wk = Wg[k * 64 + j];                    // coalesced
            #pragma unroll
            for (int v = 0; v < 16; ++v) {
                float dv = b ? data[k * 64 + vbase + v]   // broadcast
                             : data[(vbase + v) * 64 + k];
                acc[v] = fmaf(dv, wk, acc[v]);
            }
        }
        #pragma unroll
        for (int v = 0; v < 16; ++v) hb[vbase + v][j] = acc[v];
        __syncthreads();

        // star softmax per head j; node 0 has h=0 -> e=0 (ar drops out entirely)
        if (tid < 64) {
            int j2 = tid;
            float a = al[j2];
            float m = 0.f;                    // includes node-0 term e=0
            for (int v = 0; v < 64; ++v) {
                float e = hb[v][j2] * a;
                e = e > 0.f ? e : 0.2f * e;
                m = fmaxf(m, e);
            }
            float sum = __expf(0.f - m);      // node-0 term (zero numerator)
            float num = 0.f;
            for (int v = 0; v < 64; ++v) {
                float hv = hb[v][j2];
                float e  = hv * a;
                e = e > 0.f ? e : 0.2f * e;
                float p  = __expf(e - m);
                sum += p;
                num += p * hv;
            }
            out0[j2] = num / sum;
        }
        __syncthreads();

        // x[(n*64+f)*3 + c]: c0 = data_r (block 0 only), c1/c2 = gat out + bias
        for (int i = tid; i < 4160; i += 256) {
            int n = i >> 6, f = i & 63;
            float val = ((n == 0) ? out0[f] : hb[n - 1][f]) + bb[f];
            ws[X_OFF + i * 3 + 1 + b] = val;
            if (b == 0)
                ws[X_OFF + i * 3] = (n == 0) ? 0.f : data[(n - 1) * 64 + f];
        }
        __syncthreads();
        __threadfence();                       // release x device-wide
        if (tid == 0)
            __hip_atomic_fetch_add(sync, 1, __ATOMIC_RELEASE,
                                   __HIP_MEMORY_SCOPE_AGENT);
    }

    // ---------------- phase 1: W_hh @ h0 (24 rows/block, 6/wave) ----------------
    {
        int r = b * RPB + wave * RPW;
        const f4* h4 = (const f4*)h0;
        const f4* Wb = (const f4*)W_hh + (size_t)r * H4;
        float a0 = 0.f, a1 = 0.f, a2 = 0.f, a3 = 0.f, a4 = 0.f, a5 = 0.f;
        int k = lane;
        #pragma unroll 2
        for (int i = 0; i < 16; ++i, k += 64) {   // 1024 = 16*64 exactly
            f4 v = h4[k];
            a0 = fma4(ntload(Wb + k),          v, a0);
            a1 = fma4(ntload(Wb + H4 + k),     v, a1);
            a2 = fma4(ntload(Wb + 2 * H4 + k), v, a2);
            a3 = fma4(ntload(Wb + 3 * H4 + k), v, a3);
            a4 = fma4(ntload(Wb + 4 * H4 + k), v, a4);
            a5 = fma4(ntload(Wb + 5 * H4 + k), v, a5);
        }
        a0 = wave_reduce(a0); a1 = wave_reduce(a1); a2 = wave_reduce(a2);
        a3 = wave_reduce(a3); a4 = wave_reduce(a4); a5 = wave_reduce(a5);
        if (lane == 0) {
            ws[GH_OFF + r]     = a0 + b_hh[r];
            ws[GH_OFF + r + 1] = a1 + b_hh[r + 1];
            ws[GH_OFF + r + 2] = a2 + b_hh[r + 2];
            ws[GH_OFF + r + 3] = a3 + b_hh[r + 3];
            ws[GH_OFF + r + 4] = a4 + b_hh[r + 4];
            ws[GH_OFF + r + 5] = a5 + b_hh[r + 5];
        }
    }

    // ---------------- wait for x (free: GAT << phase-1 duration) ----------------
    if (tid == 0) {
        while (__hip_atomic_load(sync, __ATOMIC_RELAXED,
                                 __HIP_MEMORY_SCOPE_AGENT) < 2)
            __builtin_amdgcn_s_sleep(8);
    }
    __syncthreads();
    __threadfence();                           // acquire x (invalidate stale L2)

    // ---------------- phase 2: W_ih @ x (24 rows/block, 6/wave) -----------------
    {
        int r = b * RPB + wave * RPW;
        const f4* x4 = (const f4*)(ws + X_OFF);
        const f4* Wb = (const f4*)W_ih + (size_t)r * I4;
        float a0 = 0.f, a1 = 0.f, a2 = 0.f, a3 = 0.f, a4 = 0.f, a5 = 0.f;
        int k = lane;
        #pragma unroll 2
        for (int i = 0; i < 48; ++i, k += 64) {
            f4 v = x4[k];
            a0 = fma4(ntload(Wb + k),          v, a0);
            a1 = fma4(ntload(Wb + I4 + k),     v, a1);
            a2 = fma4(ntload(Wb + 2 * I4 + k), v, a2);
            a3 = fma4(ntload(Wb + 3 * I4 + k), v, a3);
            a4 = fma4(ntload(Wb + 4 * I4 + k), v, a4);
            a5 = fma4(ntload(Wb + 5 * I4 + k), v, a5);
        }
        if (lane < 48) {                       // remainder: 3120 = 48*64 + 48
            int kk = 3072 + lane;
            f4 v = x4[kk];
            a0 = fma4(ntload(Wb + kk),          v, a0);
            a1 = fma4(ntload(Wb + I4 + kk),     v, a1);
            a2 = fma4(ntload(Wb + 2 * I4 + kk), v, a2);
            a3 = fma4(ntload(Wb + 3 * I4 + kk), v, a3);
            a4 = fma4(ntload(Wb + 4 * I4 + kk), v, a4);
            a5 = fma4(ntload(Wb + 5 * I4 + kk), v, a5);
        }
        a0 = wave_reduce(a0); a1 = wave_reduce(a1); a2 = wave_reduce(a2);
        a3 = wave_reduce(a3); a4 = wave_reduce(a4); a5 = wave_reduce(a5);
        if (lane == 0) {
            ws[GI_OFF + r]     = a0 + b_ih[r];
            ws[GI_OFF + r + 1] = a1 + b_ih[r + 1];
            ws[GI_OFF + r + 2] = a2 + b_ih[r + 2];
            ws[GI_OFF + r + 3] = a3 + b_ih[r + 3];
            ws[GI_OFF + r + 4] = a4 + b_ih[r + 4];
            ws[GI_OFF + r + 5] = a5 + b_ih[r + 5];
        }
    }

    // ---------------- last block: GRU combine -----------------------------------
    __threadfence();                           // release gi/gh
    if (tid == 0) {
        int old = __hip_atomic_fetch_add(sync + 1, 1, __ATOMIC_ACQ_REL,
                                         __HIP_MEMORY_SCOPE_AGENT);
        sLast = (old == NBLK - 1);
    }
    __syncthreads();
    if (sLast) {
        __threadfence();                       // acquire gi/gh
        #pragma unroll
        for (int t = 0; t < 16; ++t) {
            int j = t * 256 + tid;             // 4096 = 16*256, coalesced
            float ir  = ws[GI_OFF + j];
            float iz  = ws[GI_OFF + HSZ + j];
            float in_ = ws[GI_OFF + 2 * HSZ + j];
            float hr  = ws[GH_OFF + j];
            float hz  = ws[GH_OFF + HSZ + j];
            float hn  = ws[GH_OFF + 2 * HSZ + j];
            float r = 1.f / (1.f + __expf(-(ir + hr)));
            float z = 1.f / (1.f + __expf(-(iz + hz)));
            float n = tanhf(in_ + r * hn);
            float h = (1.f - z) * n + z * h0[j];
            out[j]       = h;
            out[HSZ + j] = h;
        }
    }
}

extern "C" void kernel_launch(void* const* d_in, const int* in_sizes, int n_in,
                              void* d_out, int out_size, void* d_ws, size_t ws_size,
                              hipStream_t stream) {
    const float* data    = (const float*)d_in[0];
    const float* hidden  = (const float*)d_in[1];
    const float* fgat_W  = (const float*)d_in[2];
    const float* fgat_al = (const float*)d_in[3];
    // d_in[4] = fgat_ar (unused: er[0] = h[0]*ar = 0 since padded row 0 is zero)
    const float* fgat_b  = (const float*)d_in[5];
    const float* tgat_W  = (const float*)d_in[6];
    const float* tgat_al = (const float*)d_in[7];
    // d_in[8] = tgat_ar (unused, same reason)
    const float* tgat_b  = (const float*)d_in[9];
    const float* W_ih    = (const float*)d_in[10];
    const float* W_hh    = (const float*)d_in[11];
    const float* b_ih    = (const float*)d_in[12];
    const float* b_hh    = (const float*)d_in[13];
    float* ws  = (float*)d_ws;
    float* out = (float*)d_out;

    // zero the flag + counter (ws is poisoned once and never re-poisoned)
    hipMemsetAsync((char*)d_ws + SYNC_OFF * sizeof(float), 0, 2 * sizeof(int),
                   stream);
    mega<<<NBLK, 256, 0, stream>>>(data, fgat_W, fgat_al, fgat_b,
                                   tgat_W, tgat_al, tgat_b,
                                   W_ih, W_hh, hidden, b_ih, b_hh, ws, out);
}